// Round 5
// baseline (521.046 us; speedup 1.0000x reference)
//
#include <hip/hip_runtime.h>

static constexpr int NE   = 4096;      // n_embed
static constexpr int ED   = 64;        // embed_dim
static constexpr int NTOK = 65536;     // 4*16*32*32
static constexpr int NCHUNK = 16;      // code-loop split factor
static constexpr int CPC  = NE / NCHUNK;   // codes per chunk = 256

typedef float f32x2 __attribute__((ext_vector_type(2)));

// packed fp32 fma; scalar fallback has identical numerics (per-lane fmaf)
static __device__ __forceinline__ f32x2 pkfma(f32x2 a, f32x2 b, f32x2 c) {
#if __has_builtin(__builtin_elementwise_fma)
    return __builtin_elementwise_fma(a, b, c);
#else
    f32x2 r;
    r.x = fmaf(a.x, b.x, c.x);
    r.y = fmaf(a.y, b.y, c.y);
    return r;
#endif
}

// d_out offsets (float elements), outputs concatenated in return order:
// out(4194304), loss(1), perplexity(1), idx(65536), new_embed(262144),
// new_cs(4096), new_ea(262144)
static constexpr long O_OUT  = 0;
static constexpr long O_LOSS = 4194304;
static constexpr long O_PERP = 4194305;
static constexpr long O_IDX  = 4194306;
static constexpr long O_NEMB = 4259842;
static constexpr long O_NCS  = 4521986;
static constexpr long O_NEA  = 4526082;

// ws layout (bytes)
static constexpr size_t W_ACC   = 0;        // double[4]: [0]=loss [1]=n [2]=plog   (zeroed)
static constexpr size_t W_CNT   = 32;       // unsigned[4096] counts                (zeroed)
static constexpr size_t W_CUR   = 16416;    // unsigned[4096] scatter cursors       (zeroed)
static constexpr size_t W_OFF   = 32800;    // unsigned[4096] bucket start offsets
static constexpr size_t W_BSQ   = 49184;    // float[4096]  ||e_n||^2
static constexpr size_t W_IDX   = 65568;    // int[65536]
static constexpr size_t W_BKT   = 327712;   // int[65536] token ids bucketed by code
static constexpr size_t W_LOSSP = 589856;   // double[16384] per-block loss partials
static constexpr size_t W_PKD   = 720928;   // uint64[65536] packed (d_bits<<32)|idx
static constexpr size_t W_ZERO_BYTES = 32800;   // acc + counts + cursors
static constexpr size_t W_PKD_BYTES  = 524288;  // 0xFF-init packed

// ---- ||e_n||^2 precompute -------------------------------------------------
__global__ __launch_bounds__(256) void kBsq(const float* __restrict__ e,
                                            float* __restrict__ bsq) {
    int n = blockIdx.x * 256 + threadIdx.x;
    const float* er = e + (n << 6);
    float a0 = 0.f, a1 = 0.f, a2 = 0.f, a3 = 0.f;
#pragma unroll
    for (int k = 0; k < ED; k += 4) {
        a0 = fmaf(er[k+0], er[k+0], a0);
        a1 = fmaf(er[k+1], er[k+1], a1);
        a2 = fmaf(er[k+2], er[k+2], a2);
        a3 = fmaf(er[k+3], er[k+3], a3);
    }
    bsq[n] = (a0 + a1) + (a2 + a3);
}

// ---- argmin over a 256-code chunk, one thread per token -------------------
// grid = 4096 blocks: block = (tokenBlock<<4) | chunk
// r4 post-mortem: one-time "+v" pins let LLVM park zr2 in AGPRs (VGPR->AGPR
// spill, ~64 v_accvgpr_read per code-iter => 102 VALU insts/iter measured).
// Fix: pin all 32 pairs EVERY iteration -> AGPR parking would cost 64 reloads
// per iter, so the allocator keeps them in true VGPRs. launch_bounds(256,4)
// gives a 128-reg budget so zr2(64)+accs+addressing fits without spills.
__global__ __launch_bounds__(256, 4) void kArgmin(const float* __restrict__ z,
                                                  const float* __restrict__ e,
                                                  const float* __restrict__ bsq,
                                                  unsigned long long* __restrict__ packed) {
    int bid = blockIdx.x;
    int tb = bid >> 4;
    int chunk = bid & 15;
    int t = tb * 256 + threadIdx.x;             // token id
    int b = t >> 14;                            // batch
    int s = t & 16383;                          // d*1024+h*32+w
    const float* zp = z + (long)b * 1048576 + s;

    // zr2[j] = (z[2j], z[2j+1]) -> pk lanes reproduce the exact 4-partial
    // fp32 dot (d0..d3, k+=4) of the reference path, bit-identically.
    f32x2 zr2[ED / 2];
#pragma unroll
    for (int j = 0; j < ED / 2; ++j) {
        f32x2 v;
        v.x = zp[(2 * j + 0) * 16384];
        v.y = zp[(2 * j + 1) * 16384];
        zr2[j] = v;
    }

    // A = sum z^2: aa0 holds partials (k%4==0, k%4==1), aa1 (2,3)
    f32x2 aa0 = {0.f, 0.f}, aa1 = {0.f, 0.f};
#pragma unroll
    for (int j = 0; j < ED / 2; j += 2) {
        aa0 = pkfma(zr2[j],     zr2[j],     aa0);
        aa1 = pkfma(zr2[j + 1], zr2[j + 1], aa1);
    }
    float A = (aa0.x + aa0.y) + (aa1.x + aa1.y);   // == (a0+a1)+(a2+a3)

    float best = __builtin_inff();
    int bidx = 0;
    int c0 = chunk * CPC;
    for (int n = c0; n < c0 + CPC; ++n) {
        // in-loop VGPR pins: defeat AGPR spilling of the token vector
#pragma unroll
        for (int j = 0; j < ED / 2; ++j) asm volatile("" : "+v"(zr2[j]));
        // force wave-uniform address -> scalar (s_load) codebook row fetch
        int nu = __builtin_amdgcn_readfirstlane(n);
        const f32x2* __restrict__ er2 = (const f32x2*)(e + (nu << 6));
        float bq = bsq[nu];
        f32x2 c0v = {0.f, 0.f}, c1v = {0.f, 0.f};
#pragma unroll
        for (int j = 0; j < ED / 2; j += 2) {
            c0v = pkfma(zr2[j],     er2[j],     c0v);
            c1v = pkfma(zr2[j + 1], er2[j + 1], c1v);
        }
        float dot = (c0v.x + c0v.y) + (c1v.x + c1v.y);  // == (d0+d1)+(d2+d3)
        // d = fl((A+bq) - 2*dot): 2*dot exact, single-rounding fma == 2-op ref
        float d = fmaf(-2.0f, dot, A + bq);
        if (d < best) { best = d; bidx = n; }   // strict < == first-index ties
    }
    // d >= 0 always so float order == uint order; low 32 bits = idx so
    // equal-d ties pick the smaller index (first-occurrence argmin).
    unsigned long long pk =
        ((unsigned long long)__float_as_uint(best) << 32) | (unsigned)bidx;
    atomicMin(&packed[t], pk);
}

// ---- unpack chunk-combined argmin, emit idx + counts ----------------------
__global__ __launch_bounds__(256) void kFinish(const unsigned long long* __restrict__ packed,
                                               float* __restrict__ outIdxF,
                                               int* __restrict__ wsIdx,
                                               unsigned* __restrict__ counts) {
    int t = blockIdx.x * 256 + threadIdx.x;
    int idx = (int)(unsigned)(packed[t] & 0xFFFFFFFFull);
    outIdxF[t] = (float)idx;
    wsIdx[t]   = idx;
    atomicAdd(&counts[idx], 1u);
}

// ---- exclusive prefix sum of counts -> bucket offsets ---------------------
__global__ __launch_bounds__(256) void kOffsets(const unsigned* __restrict__ counts,
                                                unsigned* __restrict__ offsets) {
    __shared__ unsigned psum[256];
    int tid = threadIdx.x;
    unsigned local[16];
    unsigned s = 0;
#pragma unroll
    for (int j = 0; j < 16; ++j) { local[j] = s; s += counts[tid * 16 + j]; }
    psum[tid] = s;
    __syncthreads();
    unsigned base = 0;
    for (int i = 0; i < tid; ++i) base += psum[i];
#pragma unroll
    for (int j = 0; j < 16; ++j) offsets[tid * 16 + j] = base + local[j];
}

// ---- scatter token ids into per-code buckets ------------------------------
__global__ __launch_bounds__(256) void kScatter(const int* __restrict__ wsIdx,
                                                const unsigned* __restrict__ offsets,
                                                unsigned* __restrict__ cursor,
                                                int* __restrict__ bucket) {
    int t = blockIdx.x * 256 + threadIdx.x;
    int idx = wsIdx[t];
    unsigned pos = atomicAdd(&cursor[idx], 1u);
    bucket[offsets[idx] + pos] = t;
}

// ---- streaming epilogue: gather, straight-through out, loss partials ------
__global__ __launch_bounds__(256) void kEpilogue(const float* __restrict__ z,
                                                 const float* __restrict__ e,
                                                 const int* __restrict__ wsIdx,
                                                 float* __restrict__ out,
                                                 double* __restrict__ lossPart) {
    __shared__ double lp[4];
    long g = (long)blockIdx.x * 256 + threadIdx.x;   // 0 .. 4194303 (z-linear)
    int b = (int)(g >> 20);
    int r = (int)(g & 1048575);
    int k = r >> 14;
    int s = r & 16383;
    int t = (b << 14) | s;

    float zv = z[g];
    int n = wsIdx[t];
    float eq = e[(n << 6) + k];
    float diff = eq - zv;            // fl(z_q - zp)
    out[g] = zv + diff;              // fl(zp + fl(z_q - zp))  (straight-through)

    double sq = (double)diff * (double)diff;
#pragma unroll
    for (int o = 32; o > 0; o >>= 1) sq += __shfl_down(sq, o);
    if ((threadIdx.x & 63) == 0) lp[threadIdx.x >> 6] = sq;
    __syncthreads();
    if (threadIdx.x == 0) lossPart[blockIdx.x] = (lp[0] + lp[1]) + (lp[2] + lp[3]);
}

// ---- reduce loss partials -------------------------------------------------
__global__ __launch_bounds__(256) void kLoss(const double* __restrict__ lossPart,
                                             double* __restrict__ acc) {
    __shared__ double lp[4];
    double s = 0.0;
    for (int j = 0; j < 64; ++j) s += lossPart[threadIdx.x + j * 256];
#pragma unroll
    for (int o = 32; o > 0; o >>= 1) s += __shfl_down(s, o);
    if ((threadIdx.x & 63) == 0) lp[threadIdx.x >> 6] = s;
    __syncthreads();
    if (threadIdx.x == 0) acc[0] = (lp[0] + lp[1]) + (lp[2] + lp[3]);
}

// ---- EMA part 1: new_cs, n-sum, perplexity partial ------------------------
__global__ __launch_bounds__(256) void kEma1(const float* __restrict__ cs,
                                             const unsigned* __restrict__ counts,
                                             float* __restrict__ outNcs,
                                             double* __restrict__ acc) {
    int n = blockIdx.x * 256 + threadIdx.x;
    float cf = (float)counts[n];
    float p1 = cs[n] * 0.99f;
    float p2 = 0.01f * cf;
    float ncs = p1 + p2;
    outNcs[n] = ncs;
    float p = cf * (1.0f / 65536.0f);          // exact (pow2 divide)
    float term = p * logf(p + 1e-10f);
    double dn = (double)ncs, dt = (double)term;
#pragma unroll
    for (int o = 32; o > 0; o >>= 1) { dn += __shfl_down(dn, o); dt += __shfl_down(dt, o); }
    if ((threadIdx.x & 63) == 0) {
        atomicAdd(&acc[1], dn);
        atomicAdd(&acc[2], dt);
    }
}

// ---- per-code bucket gather: embed_sum -> new_ea, new_embed; scalars ------
__global__ __launch_bounds__(64) void kEsumEma2(const float* __restrict__ z,
                                                const float* __restrict__ ea,
                                                const int* __restrict__ bucket,
                                                const unsigned* __restrict__ offsets,
                                                const unsigned* __restrict__ counts,
                                                const float* __restrict__ ncsArr,
                                                const double* __restrict__ acc,
                                                float* __restrict__ outNemb,
                                                float* __restrict__ outNea,
                                                float* __restrict__ outLoss,
                                                float* __restrict__ outPerp) {
    int n = blockIdx.x;              // code id
    int k = threadIdx.x;             // dim
    unsigned off = offsets[n];
    unsigned cnt = counts[n];
    float es = 0.f;
    for (unsigned i = 0; i < cnt; ++i) {
        int t = bucket[off + i];
        int b = t >> 14;
        int s = t & 16383;
        es += z[(long)b * 1048576 + k * 16384 + s];
    }
    float nea = ea[(n << 6) + k] * 0.99f + 0.01f * es;
    outNea[(n << 6) + k] = nea;
    float nt = (float)acc[1];
    float ncs = ncsArr[n];
    float sc = ((ncs + 1e-5f) / (nt + 0.04096f)) * nt;
    outNemb[(n << 6) + k] = nea / sc;
    if (n == 0 && k == 0) {
        double m = acc[0] / 4194304.0;
        outLoss[0] = 0.25f * (float)m;
        outPerp[0] = (float)exp(-acc[2]);
    }
}

extern "C" void kernel_launch(void* const* d_in, const int* in_sizes, int n_in,
                              void* d_out, int out_size, void* d_ws, size_t ws_size,
                              hipStream_t stream) {
    const float* z  = (const float*)d_in[0];
    const float* ew = (const float*)d_in[1];
    const float* cs = (const float*)d_in[2];
    const float* ea = (const float*)d_in[3];
    float* out = (float*)d_out;
    char* ws = (char*)d_ws;

    double*   acc    = (double*)(ws + W_ACC);
    unsigned* counts = (unsigned*)(ws + W_CNT);
    unsigned* cursor = (unsigned*)(ws + W_CUR);
    unsigned* offs   = (unsigned*)(ws + W_OFF);
    float*    bsq    = (float*)(ws + W_BSQ);
    int*      wsIdx  = (int*)(ws + W_IDX);
    int*      bucket = (int*)(ws + W_BKT);
    double*   lossP  = (double*)(ws + W_LOSSP);
    unsigned long long* packed = (unsigned long long*)(ws + W_PKD);

    hipMemsetAsync(ws, 0, W_ZERO_BYTES, stream);
    hipMemsetAsync(ws + W_PKD, 0xFF, W_PKD_BYTES, stream);
    kBsq<<<NE / 256, 256, 0, stream>>>(ew, bsq);
    kArgmin<<<(NTOK / 256) * NCHUNK, 256, 0, stream>>>(z, ew, bsq, packed);
    kFinish<<<NTOK / 256, 256, 0, stream>>>(packed, out + O_IDX, wsIdx, counts);
    kOffsets<<<1, 256, 0, stream>>>(counts, offs);
    kScatter<<<NTOK / 256, 256, 0, stream>>>(wsIdx, offs, cursor, bucket);
    kEpilogue<<<16384, 256, 0, stream>>>(z, ew, wsIdx, out + O_OUT, lossP);
    kLoss<<<1, 256, 0, stream>>>(lossP, acc);
    kEma1<<<NE / 256, 256, 0, stream>>>(cs, counts, out + O_NCS, acc);
    kEsumEma2<<<NE, 64, 0, stream>>>(z, ea, bucket, offs, counts, out + O_NCS, acc,
                                     out + O_NEMB, out + O_NEA,
                                     out + O_LOSS, out + O_PERP);
}

// Round 6
// 509.303 us; speedup vs baseline: 1.0231x; 1.0231x over previous
//
#include <hip/hip_runtime.h>

static constexpr int NE   = 4096;      // n_embed
static constexpr int ED   = 64;        // embed_dim
static constexpr int NTOK = 65536;     // 4*16*32*32
static constexpr int NCHUNK = 16;      // code-loop split factor
static constexpr int CPC  = NE / NCHUNK;   // codes per chunk = 256

typedef float f32x2 __attribute__((ext_vector_type(2)));

// packed fp32 fma; scalar fallback has identical numerics (per-lane fmaf)
static __device__ __forceinline__ f32x2 pkfma(f32x2 a, f32x2 b, f32x2 c) {
#if __has_builtin(__builtin_elementwise_fma)
    return __builtin_elementwise_fma(a, b, c);
#else
    f32x2 r;
    r.x = fmaf(a.x, b.x, c.x);
    r.y = fmaf(a.y, b.y, c.y);
    return r;
#endif
}

// d_out offsets (float elements), outputs concatenated in return order:
// out(4194304), loss(1), perplexity(1), idx(65536), new_embed(262144),
// new_cs(4096), new_ea(262144)
static constexpr long O_OUT  = 0;
static constexpr long O_LOSS = 4194304;
static constexpr long O_PERP = 4194305;
static constexpr long O_IDX  = 4194306;
static constexpr long O_NEMB = 4259842;
static constexpr long O_NCS  = 4521986;
static constexpr long O_NEA  = 4526082;

// ws layout (bytes)
static constexpr size_t W_ACC   = 0;        // double[4]: [0]=loss [1]=n [2]=plog   (zeroed)
static constexpr size_t W_CNT   = 32;       // unsigned[4096] counts                (zeroed)
static constexpr size_t W_CUR   = 16416;    // unsigned[4096] scatter cursors       (zeroed)
static constexpr size_t W_OFF   = 32800;    // unsigned[4096] bucket start offsets
static constexpr size_t W_BSQ   = 49184;    // float[4096]  ||e_n||^2
static constexpr size_t W_IDX   = 65568;    // int[65536]
static constexpr size_t W_BKT   = 327712;   // int[65536] token ids bucketed by code
static constexpr size_t W_LOSSP = 589856;   // double[16384] per-block loss partials
static constexpr size_t W_PKD   = 720928;   // uint64[65536] packed (d_bits<<32)|idx
static constexpr size_t W_ZERO_BYTES = 32800;   // acc + counts + cursors
static constexpr size_t W_PKD_BYTES  = 524288;  // 0xFF-init packed

// ---- ||e_n||^2 precompute -------------------------------------------------
__global__ __launch_bounds__(256) void kBsq(const float* __restrict__ e,
                                            float* __restrict__ bsq) {
    int n = blockIdx.x * 256 + threadIdx.x;
    const float* er = e + (n << 6);
    float a0 = 0.f, a1 = 0.f, a2 = 0.f, a3 = 0.f;
#pragma unroll
    for (int k = 0; k < ED; k += 4) {
        a0 = fmaf(er[k+0], er[k+0], a0);
        a1 = fmaf(er[k+1], er[k+1], a1);
        a2 = fmaf(er[k+2], er[k+2], a2);
        a3 = fmaf(er[k+3], er[k+3], a3);
    }
    bsq[n] = (a0 + a1) + (a2 + a3);
}

// 32 named f32x2 registers Z0..Z31 (NOT an array: r5 post-mortem showed the
// allocator treats f32x2 zr2[32] as one contiguous 64-reg tuple and parks it
// in AGPRs -> ~75 v_accvgpr_read VALU insts per code-iter. Named independent
// variables have no contiguity constraint.)
#define Z_EACH(F) \
    F(0)  F(1)  F(2)  F(3)  F(4)  F(5)  F(6)  F(7)  \
    F(8)  F(9)  F(10) F(11) F(12) F(13) F(14) F(15) \
    F(16) F(17) F(18) F(19) F(20) F(21) F(22) F(23) \
    F(24) F(25) F(26) F(27) F(28) F(29) F(30) F(31)

// ---- argmin over a 256-code chunk, one thread per token -------------------
// grid = 4096 blocks: block = (tokenBlock<<4) | chunk
__global__ __launch_bounds__(256, 4) void kArgmin(const float* __restrict__ z,
                                                  const float* __restrict__ e,
                                                  const float* __restrict__ bsq,
                                                  unsigned long long* __restrict__ packed) {
    int bid = blockIdx.x;
    int tb = bid >> 4;
    int chunk = bid & 15;
    int t = tb * 256 + threadIdx.x;             // token id
    int b = t >> 14;                            // batch
    int s = t & 16383;                          // d*1024+h*32+w
    const float* zp = z + (long)b * 1048576 + s;

    // ZJ = (z[2J], z[2J+1]) -> pk lanes reproduce the exact 4-partial fp32
    // dot (d0..d3 over k%4, k+=4) of the reference path, bit-identically.
#define Z_LOAD(J) f32x2 Z##J; Z##J.x = zp[(2*J)   * 16384]; \
                              Z##J.y = zp[(2*J+1) * 16384];
    Z_EACH(Z_LOAD)
#undef Z_LOAD

    // A = sum z^2: aa0 accumulates even pairs (k%4 in {0,1}), aa1 odd ({2,3}),
    // ascending order — identical to the r4/r5 passing kernel.
    f32x2 aa0 = {0.f, 0.f}, aa1 = {0.f, 0.f};
#define Z_ASUM(J) { if ((J & 1) == 0) aa0 = pkfma(Z##J, Z##J, aa0); \
                    else              aa1 = pkfma(Z##J, Z##J, aa1); }
    Z_EACH(Z_ASUM)
#undef Z_ASUM
    float A = (aa0.x + aa0.y) + (aa1.x + aa1.y);   // == (a0+a1)+(a2+a3)

    float best = __builtin_inff();
    int bidx = 0;
    int c0 = chunk * CPC;
    for (int n = c0; n < c0 + CPC; ++n) {
        // force wave-uniform address -> scalar (s_load) codebook row fetch
        int nu = __builtin_amdgcn_readfirstlane(n);
        const f32x2* __restrict__ er2 = (const f32x2*)(e + (nu << 6));
        float bq = bsq[nu];
        f32x2 c0v = {0.f, 0.f}, c1v = {0.f, 0.f};
#define Z_DOT(J) { if ((J & 1) == 0) c0v = pkfma(Z##J, er2[J], c0v); \
                   else              c1v = pkfma(Z##J, er2[J], c1v); }
        Z_EACH(Z_DOT)
#undef Z_DOT
        float dot = (c0v.x + c0v.y) + (c1v.x + c1v.y);  // == (d0+d1)+(d2+d3)
        // d = fl((A+bq) - 2*dot): 2*dot exact, single-rounding fma == 2-op ref
        float d = fmaf(-2.0f, dot, A + bq);
        if (d < best) { best = d; bidx = n; }   // strict < == first-index ties
    }
    // d >= 0 always so float order == uint order; low 32 bits = idx so
    // equal-d ties pick the smaller index (first-occurrence argmin).
    unsigned long long pk =
        ((unsigned long long)__float_as_uint(best) << 32) | (unsigned)bidx;
    atomicMin(&packed[t], pk);
}

// ---- unpack chunk-combined argmin, emit idx + counts ----------------------
__global__ __launch_bounds__(256) void kFinish(const unsigned long long* __restrict__ packed,
                                               float* __restrict__ outIdxF,
                                               int* __restrict__ wsIdx,
                                               unsigned* __restrict__ counts) {
    int t = blockIdx.x * 256 + threadIdx.x;
    int idx = (int)(unsigned)(packed[t] & 0xFFFFFFFFull);
    outIdxF[t] = (float)idx;
    wsIdx[t]   = idx;
    atomicAdd(&counts[idx], 1u);
}

// ---- exclusive prefix sum of counts -> bucket offsets ---------------------
__global__ __launch_bounds__(256) void kOffsets(const unsigned* __restrict__ counts,
                                                unsigned* __restrict__ offsets) {
    __shared__ unsigned psum[256];
    int tid = threadIdx.x;
    unsigned local[16];
    unsigned s = 0;
#pragma unroll
    for (int j = 0; j < 16; ++j) { local[j] = s; s += counts[tid * 16 + j]; }
    psum[tid] = s;
    __syncthreads();
    unsigned base = 0;
    for (int i = 0; i < tid; ++i) base += psum[i];
#pragma unroll
    for (int j = 0; j < 16; ++j) offsets[tid * 16 + j] = base + local[j];
}

// ---- scatter token ids into per-code buckets ------------------------------
__global__ __launch_bounds__(256) void kScatter(const int* __restrict__ wsIdx,
                                                const unsigned* __restrict__ offsets,
                                                unsigned* __restrict__ cursor,
                                                int* __restrict__ bucket) {
    int t = blockIdx.x * 256 + threadIdx.x;
    int idx = wsIdx[t];
    unsigned pos = atomicAdd(&cursor[idx], 1u);
    bucket[offsets[idx] + pos] = t;
}

// ---- streaming epilogue: gather, straight-through out, loss partials ------
__global__ __launch_bounds__(256) void kEpilogue(const float* __restrict__ z,
                                                 const float* __restrict__ e,
                                                 const int* __restrict__ wsIdx,
                                                 float* __restrict__ out,
                                                 double* __restrict__ lossPart) {
    __shared__ double lp[4];
    long g = (long)blockIdx.x * 256 + threadIdx.x;   // 0 .. 4194303 (z-linear)
    int b = (int)(g >> 20);
    int r = (int)(g & 1048575);
    int k = r >> 14;
    int s = r & 16383;
    int t = (b << 14) | s;

    float zv = z[g];
    int n = wsIdx[t];
    float eq = e[(n << 6) + k];
    float diff = eq - zv;            // fl(z_q - zp)
    out[g] = zv + diff;              // fl(zp + fl(z_q - zp))  (straight-through)

    double sq = (double)diff * (double)diff;
#pragma unroll
    for (int o = 32; o > 0; o >>= 1) sq += __shfl_down(sq, o);
    if ((threadIdx.x & 63) == 0) lp[threadIdx.x >> 6] = sq;
    __syncthreads();
    if (threadIdx.x == 0) lossPart[blockIdx.x] = (lp[0] + lp[1]) + (lp[2] + lp[3]);
}

// ---- reduce loss partials -------------------------------------------------
__global__ __launch_bounds__(256) void kLoss(const double* __restrict__ lossPart,
                                             double* __restrict__ acc) {
    __shared__ double lp[4];
    double s = 0.0;
    for (int j = 0; j < 64; ++j) s += lossPart[threadIdx.x + j * 256];
#pragma unroll
    for (int o = 32; o > 0; o >>= 1) s += __shfl_down(s, o);
    if ((threadIdx.x & 63) == 0) lp[threadIdx.x >> 6] = s;
    __syncthreads();
    if (threadIdx.x == 0) acc[0] = (lp[0] + lp[1]) + (lp[2] + lp[3]);
}

// ---- EMA part 1: new_cs, n-sum, perplexity partial ------------------------
__global__ __launch_bounds__(256) void kEma1(const float* __restrict__ cs,
                                             const unsigned* __restrict__ counts,
                                             float* __restrict__ outNcs,
                                             double* __restrict__ acc) {
    int n = blockIdx.x * 256 + threadIdx.x;
    float cf = (float)counts[n];
    float p1 = cs[n] * 0.99f;
    float p2 = 0.01f * cf;
    float ncs = p1 + p2;
    outNcs[n] = ncs;
    float p = cf * (1.0f / 65536.0f);          // exact (pow2 divide)
    float term = p * logf(p + 1e-10f);
    double dn = (double)ncs, dt = (double)term;
#pragma unroll
    for (int o = 32; o > 0; o >>= 1) { dn += __shfl_down(dn, o); dt += __shfl_down(dt, o); }
    if ((threadIdx.x & 63) == 0) {
        atomicAdd(&acc[1], dn);
        atomicAdd(&acc[2], dt);
    }
}

// ---- per-code bucket gather: embed_sum -> new_ea, new_embed; scalars ------
__global__ __launch_bounds__(64) void kEsumEma2(const float* __restrict__ z,
                                                const float* __restrict__ ea,
                                                const int* __restrict__ bucket,
                                                const unsigned* __restrict__ offsets,
                                                const unsigned* __restrict__ counts,
                                                const float* __restrict__ ncsArr,
                                                const double* __restrict__ acc,
                                                float* __restrict__ outNemb,
                                                float* __restrict__ outNea,
                                                float* __restrict__ outLoss,
                                                float* __restrict__ outPerp) {
    int n = blockIdx.x;              // code id
    int k = threadIdx.x;             // dim
    unsigned off = offsets[n];
    unsigned cnt = counts[n];
    float es = 0.f;
    for (unsigned i = 0; i < cnt; ++i) {
        int t = bucket[off + i];
        int b = t >> 14;
        int s = t & 16383;
        es += z[(long)b * 1048576 + k * 16384 + s];
    }
    float nea = ea[(n << 6) + k] * 0.99f + 0.01f * es;
    outNea[(n << 6) + k] = nea;
    float nt = (float)acc[1];
    float ncs = ncsArr[n];
    float sc = ((ncs + 1e-5f) / (nt + 0.04096f)) * nt;
    outNemb[(n << 6) + k] = nea / sc;
    if (n == 0 && k == 0) {
        double m = acc[0] / 4194304.0;
        outLoss[0] = 0.25f * (float)m;
        outPerp[0] = (float)exp(-acc[2]);
    }
}

extern "C" void kernel_launch(void* const* d_in, const int* in_sizes, int n_in,
                              void* d_out, int out_size, void* d_ws, size_t ws_size,
                              hipStream_t stream) {
    const float* z  = (const float*)d_in[0];
    const float* ew = (const float*)d_in[1];
    const float* cs = (const float*)d_in[2];
    const float* ea = (const float*)d_in[3];
    float* out = (float*)d_out;
    char* ws = (char*)d_ws;

    double*   acc    = (double*)(ws + W_ACC);
    unsigned* counts = (unsigned*)(ws + W_CNT);
    unsigned* cursor = (unsigned*)(ws + W_CUR);
    unsigned* offs   = (unsigned*)(ws + W_OFF);
    float*    bsq    = (float*)(ws + W_BSQ);
    int*      wsIdx  = (int*)(ws + W_IDX);
    int*      bucket = (int*)(ws + W_BKT);
    double*   lossP  = (double*)(ws + W_LOSSP);
    unsigned long long* packed = (unsigned long long*)(ws + W_PKD);

    hipMemsetAsync(ws, 0, W_ZERO_BYTES, stream);
    hipMemsetAsync(ws + W_PKD, 0xFF, W_PKD_BYTES, stream);
    kBsq<<<NE / 256, 256, 0, stream>>>(ew, bsq);
    kArgmin<<<(NTOK / 256) * NCHUNK, 256, 0, stream>>>(z, ew, bsq, packed);
    kFinish<<<NTOK / 256, 256, 0, stream>>>(packed, out + O_IDX, wsIdx, counts);
    kOffsets<<<1, 256, 0, stream>>>(counts, offs);
    kScatter<<<NTOK / 256, 256, 0, stream>>>(wsIdx, offs, cursor, bucket);
    kEpilogue<<<16384, 256, 0, stream>>>(z, ew, wsIdx, out + O_OUT, lossP);
    kLoss<<<1, 256, 0, stream>>>(lossP, acc);
    kEma1<<<NE / 256, 256, 0, stream>>>(cs, counts, out + O_NCS, acc);
    kEsumEma2<<<NE, 64, 0, stream>>>(z, ea, bucket, offs, counts, out + O_NCS, acc,
                                     out + O_NEMB, out + O_NEA,
                                     out + O_LOSS, out + O_PERP);
}